// Round 6
// baseline (48.095 us; speedup 1.0000x reference)
//
#include <hip/hip_runtime.h>
#include <math.h>

#define PI_F 3.14159265358979323846f

// QuantumProjection — R16: R15 base, ONE change: remove the unnecessary barrier.
// R15 post-mortem (WIN 50.3->46.1): VALU shrank as predicted (22%->14%, abs ~11.4us).
// Remaining gap vs phase-sum model (~35us) ~ 10us. Structural observation: the
// __syncthreads in R12/R14/R15 is dead — wave wid writes angLds[wid*16..] and reads
// ONLY its own slice; no cross-wave data flow. Its only effect: re-synchronize the
// block's waves each iteration == enforce chip-wide lockstep {read burst, compute
// bubble, write burst} (streams never mix; R12 lesson). R16 deletes LDS+barrier,
// using R13's PROVEN shuffle redistribution (R13 passed; its regression was
// occupancy/ILP, not correctness): angles stay in regs a[0..3] (one per pass, valid
// on all lanes, duplicated mod 16); comb = a[lane>>4] via 2 selects; 4 __shfl from
// same-16-group lane (lane&48) + 4*((lane>>2)&3) + w. Waves drift freely ->
// read/write phase mixing grows with natural memory jitter.
// Kept: R7 (no reg cap), R9 (plain x loads; L3 half-residency, FETCH~66MB),
// R14 (plain stores == NT), R15 split-state circuit (4 amps/lane).

typedef float floatx4 __attribute__((ext_vector_type(4)));

static __device__ __forceinline__ void st_store4(float* p, floatx4 v)
{
    *reinterpret_cast<floatx4*>(p) = v;
}

static __device__ __forceinline__ float fast_tanh(float a)
{
    a = fminf(fmaxf(a, -15.f), 15.f);
    const float e = __expf(2.f * a);
    return (e - 1.f) / (e + 1.f);
}

// ---- split-state Rot helpers (R15, unchanged) ----
template<int ST>
__device__ __forceinline__ void rot_inlane(float* ar, float* ai,
    float u00r, float u00i, float u01r, float u01i,
    float u10r, float u10i, float u11r, float u11i)
{
#pragma unroll
    for (int k = 0; k < 4; ++k) {
        if (k & ST) continue;
        const int j = k | ST;
        const float Ar = ar[k], Ai = ai[k], Br = ar[j], Bi = ai[j];
        ar[k] = u00r*Ar - u00i*Ai + u01r*Br - u01i*Bi;
        ai[k] = u00r*Ai + u00i*Ar + u01r*Bi + u01i*Br;
        ar[j] = u10r*Ar - u10i*Ai + u11r*Br - u11i*Bi;
        ai[j] = u10r*Ai + u10i*Ar + u11r*Bi + u11i*Br;
    }
}

template<int XM>
__device__ __forceinline__ void rot_cross(float* ar, float* ai, bool ownB,
    float u00r, float u00i, float u01r, float u01i,
    float u10r, float u10i, float u11r, float u11i)
{
    const float cAr = ownB ? u11r : u00r;
    const float cAi = ownB ? u11i : u00i;
    const float cBr = ownB ? u10r : u01r;
    const float cBi = ownB ? u10i : u01i;
#pragma unroll
    for (int k = 0; k < 4; ++k) {
        const float pr = __shfl_xor(ar[k], XM, 64);
        const float pi = __shfl_xor(ai[k], XM, 64);
        const float vr = ar[k], vi = ai[k];
        ar[k] = cAr*vr - cAi*vi + cBr*pr - cBi*pi;
        ai[k] = cAr*vi + cAi*vr + cBr*pi + cBi*pr;
    }
}

#define ROT_COEFFS(L, W) \
    const float ph = wts[((L)*4+(W))*3+0]; \
    const float th = wts[((L)*4+(W))*3+1]; \
    const float om = wts[((L)*4+(W))*3+2]; \
    const float s_  = __sinf(0.5f*th),        c_  = __cosf(0.5f*th); \
    const float sp_ = __sinf(0.5f*(ph+om)),   cp_ = __cosf(0.5f*(ph+om)); \
    const float sq_ = __sinf(0.5f*(ph-om)),   cq_ = __cosf(0.5f*(ph-om));

#define U_ARGS cp_*c_, -sp_*c_, -cq_*s_, -sq_*s_, cq_*s_, -sq_*s_, cp_*c_, sp_*c_

// Block = 256 threads = 4 waves = 64 samples. No LDS, no barriers.
__global__ __launch_bounds__(256) void k_fused(
    const float* __restrict__ x,
    const float* __restrict__ preW,
    const float* __restrict__ preb,
    const float* __restrict__ wts,
    const float* __restrict__ postW,
    const float* __restrict__ postb,
    float* __restrict__ out, int B)
{
    const int lane  = threadIdx.x & 63;
    const int wid   = threadIdx.x >> 6;          // wave in block, 0..3
    const int base  = blockIdx.x * 64;           // 64 samples per block
    const int wbase = base + wid * 16;           // this wave's 16 samples
    if (base >= B) return;

    // ---------- Phase 1: angles (K1 structure, 4 passes) -> registers ----------
    float4 wA[4], wB[4];
#pragma unroll
    for (int w = 0; w < 4; ++w) {
        wA[w] = *reinterpret_cast<const float4*>(preW + w * 512 + lane * 4);
        wB[w] = *reinterpret_cast<const float4*>(preW + w * 512 + 256 + lane * 4);
    }
    const float4 pb = *reinterpret_cast<const float4*>(preb);
    const float pb01 = (lane & 1) ? pb.y : pb.x;
    const float pb23 = (lane & 1) ? pb.w : pb.z;
    const float pbv  = (lane & 2) ? pb23 : pb01;

    float a[4];                                  // fold result of pass p (all lanes valid)
#pragma unroll
    for (int p = 0; p < 4; ++p) {
        const int b0 = wbase + p * 4;

        float4 xa[4], xb[4];
#pragma unroll
        for (int t = 0; t < 4; ++t) {
            const float* xr = x + (size_t)(b0 + t) * 512;
            xa[t] = *reinterpret_cast<const float4*>(xr + lane * 4);
            xb[t] = *reinterpret_cast<const float4*>(xr + 256 + lane * 4);
        }

        float acc[4][4];
#pragma unroll
        for (int t = 0; t < 4; ++t) {
#pragma unroll
            for (int w = 0; w < 4; ++w) {
                acc[t][w] = xa[t].x * wA[w].x + xa[t].y * wA[w].y + xa[t].z * wA[w].z + xa[t].w * wA[w].w
                          + xb[t].x * wB[w].x + xb[t].y * wB[w].y + xb[t].z * wB[w].z + xb[t].w * wB[w].w;
            }
        }

        // 17-shfl fold; after xor16/xor32 result duplicated mod 16:
        // lane l holds angle(sample b0 + ((l>>2)&3), wire l&3)
        float v[4];
#pragma unroll
        for (int t = 0; t < 4; ++t) {
            float a01 = (lane & 1) ? acc[t][1] : acc[t][0];
            float b01 = (lane & 1) ? acc[t][0] : acc[t][1];
            a01 += __shfl_xor(b01, 1, 64);
            float a23 = (lane & 1) ? acc[t][3] : acc[t][2];
            float b23 = (lane & 1) ? acc[t][2] : acc[t][3];
            a23 += __shfl_xor(b23, 1, 64);
            const float vv = (lane & 2) ? a23 : a01;
            const float uu = (lane & 2) ? a01 : a23;
            v[t] = vv + __shfl_xor(uu, 2, 64);
        }
        float c01 = (lane & 4) ? v[1] : v[0];
        float d01 = (lane & 4) ? v[0] : v[1];
        c01 += __shfl_xor(d01, 4, 64);
        float c23 = (lane & 4) ? v[3] : v[2];
        float d23 = (lane & 4) ? v[2] : v[3];
        c23 += __shfl_xor(d23, 4, 64);
        float m = (lane & 8) ? c23 : c01;
        float n = (lane & 8) ? c01 : c23;
        m += __shfl_xor(n, 8, 64);
        m += __shfl_xor(m, 16, 64);
        m += __shfl_xor(m, 32, 64);

        a[p] = fast_tanh(m + pbv) * PI_F;
    }

    // ---------- shuffle redistribution (R13 mechanism, proven) ----------
    // lane l simulates sample sid=l>>2; its pass p = l>>4; comb = a[l>>4] on every
    // lane; src lane (l&48) + 4*((l>>2)&3) + w is in the same 16-group, whose comb
    // holds pass p's fold value for sample-in-pass (l>>2)&3, wire w.
    const float comb = (lane & 32) ? ((lane & 16) ? a[3] : a[2])
                                   : ((lane & 16) ? a[1] : a[0]);
    const int sb = (lane & 48) + 4 * ((lane >> 2) & 3);
    const float A0 = __shfl(comb, sb + 0, 64);
    const float A1 = __shfl(comb, sb + 1, 64);
    const float A2 = __shfl(comb, sb + 2, 64);
    const float A3 = __shfl(comb, sb + 3, 64);

    // ---------- Phase 2: SPLIT-STATE circuit (R15, unchanged) ----------
    const bool lb3 = (lane & 2) != 0;            // amp bit3 (wire0)
    const bool lb2 = (lane & 1) != 0;            // amp bit2 (wire1)

    const float s0 = __sinf(0.5f * A0), c0 = __cosf(0.5f * A0);
    const float s1 = __sinf(0.5f * A1), c1 = __cosf(0.5f * A1);
    const float s2 = __sinf(0.5f * A2), c2 = __cosf(0.5f * A2);
    const float s3 = __sinf(0.5f * A3), c3 = __cosf(0.5f * A3);

    const float mhi = (lb3 ? s0 : c0) * (lb2 ? s1 : c1);
    const float hr  = lb3 ? (lb2 ? -mhi : 0.f) : (lb2 ? 0.f : mhi);
    const float hi  = (lb3 != lb2) ? -mhi : 0.f;
    const float low0 = c2 * c3, low1 = c2 * s3, low2 = s2 * c3, low3 = s2 * s3;

    float ar[4], ai[4];
    ar[0] =  hr * low0;  ai[0] =  hi * low0;
    ar[1] =  hi * low1;  ai[1] = -hr * low1;
    ar[2] =  hi * low2;  ai[2] = -hr * low2;
    ar[3] = -hr * low3;  ai[3] = -hi * low3;

    // ---- layer 0 ----
    { ROT_COEFFS(0, 0); rot_cross<2>(ar, ai, lb3, U_ARGS); }
    { ROT_COEFFS(0, 1); rot_cross<1>(ar, ai, lb2, U_ARGS); }
    { ROT_COEFFS(0, 2); rot_inlane<2>(ar, ai, U_ARGS); }
    { ROT_COEFFS(0, 3); rot_inlane<1>(ar, ai, U_ARGS); }

    {   // cnot<0,1>
#pragma unroll
        for (int k = 0; k < 4; ++k) {
            const float tr = __shfl_xor(ar[k], 1, 64);
            const float ti = __shfl_xor(ai[k], 1, 64);
            ar[k] = lb3 ? tr : ar[k];
            ai[k] = lb3 ? ti : ai[k];
        }
    }
    {   // cnot<1,2>
        const float t0r = ar[0], t0i = ai[0], t1r = ar[1], t1i = ai[1];
        ar[0] = lb2 ? ar[2] : ar[0];  ai[0] = lb2 ? ai[2] : ai[0];
        ar[1] = lb2 ? ar[3] : ar[1];  ai[1] = lb2 ? ai[3] : ai[1];
        ar[2] = lb2 ? t0r   : ar[2];  ai[2] = lb2 ? t0i   : ai[2];
        ar[3] = lb2 ? t1r   : ar[3];  ai[3] = lb2 ? t1i   : ai[3];
    }
    {   // cnot<2,3>: in-lane swap k2<->k3
        float t;
        t = ar[2]; ar[2] = ar[3]; ar[3] = t;
        t = ai[2]; ai[2] = ai[3]; ai[3] = t;
    }
    {   // cnot<3,0>: k in {1,3} exchange across lane^2
        ar[1] = __shfl_xor(ar[1], 2, 64);  ai[1] = __shfl_xor(ai[1], 2, 64);
        ar[3] = __shfl_xor(ar[3], 2, 64);  ai[3] = __shfl_xor(ai[3], 2, 64);
    }

    // ---- layer 1 ----
    { ROT_COEFFS(1, 0); rot_cross<2>(ar, ai, lb3, U_ARGS); }
    { ROT_COEFFS(1, 1); rot_cross<1>(ar, ai, lb2, U_ARGS); }
    { ROT_COEFFS(1, 2); rot_inlane<2>(ar, ai, U_ARGS); }
    { ROT_COEFFS(1, 3); rot_inlane<1>(ar, ai, U_ARGS); }

    {   // cnot<0,2>
        const float t0r = ar[0], t0i = ai[0], t1r = ar[1], t1i = ai[1];
        ar[0] = lb3 ? ar[2] : ar[0];  ai[0] = lb3 ? ai[2] : ai[0];
        ar[1] = lb3 ? ar[3] : ar[1];  ai[1] = lb3 ? ai[3] : ai[1];
        ar[2] = lb3 ? t0r   : ar[2];  ai[2] = lb3 ? t0i   : ai[2];
        ar[3] = lb3 ? t1r   : ar[3];  ai[3] = lb3 ? t1i   : ai[3];
    }
    {   // cnot<1,3>
        const float t0r = ar[0], t0i = ai[0], t2r = ar[2], t2i = ai[2];
        ar[0] = lb2 ? ar[1] : ar[0];  ai[0] = lb2 ? ai[1] : ai[0];
        ar[1] = lb2 ? t0r   : ar[1];  ai[1] = lb2 ? t0i   : ai[1];
        ar[2] = lb2 ? ar[3] : ar[2];  ai[2] = lb2 ? ai[3] : ai[2];
        ar[3] = lb2 ? t2r   : ar[3];  ai[3] = lb2 ? t2i   : ai[3];
    }
    {   // cnot<2,0>: k in {2,3} exchange across lane^2
        ar[2] = __shfl_xor(ar[2], 2, 64);  ai[2] = __shfl_xor(ai[2], 2, 64);
        ar[3] = __shfl_xor(ar[3], 2, 64);  ai[3] = __shfl_xor(ai[3], 2, 64);
    }
    {   // cnot<3,1>: k in {1,3} exchange across lane^1
        ar[1] = __shfl_xor(ar[1], 1, 64);  ai[1] = __shfl_xor(ai[1], 1, 64);
        ar[3] = __shfl_xor(ar[3], 1, 64);  ai[3] = __shfl_xor(ai[3], 1, 64);
    }

    // ---- PauliZ expvals: per-lane partials + 4-lane group xor-reduce ----
    const float p0 = ar[0]*ar[0] + ai[0]*ai[0];
    const float p1 = ar[1]*ar[1] + ai[1]*ai[1];
    const float p2 = ar[2]*ar[2] + ai[2]*ai[2];
    const float p3 = ar[3]*ar[3] + ai[3]*ai[3];
    const float s01 = p0 + p1, s23 = p2 + p3;
    const float sum = s01 + s23;
    float z0 = lb3 ? -sum : sum;
    float z1 = lb2 ? -sum : sum;
    float z2 = s01 - s23;
    float z3 = (p0 - p1) + (p2 - p3);
    z0 += __shfl_xor(z0, 1, 64);  z0 += __shfl_xor(z0, 2, 64);
    z1 += __shfl_xor(z1, 1, 64);  z1 += __shfl_xor(z1, 2, 64);
    z2 += __shfl_xor(z2, 1, 64);  z2 += __shfl_xor(z2, 2, 64);
    z3 += __shfl_xor(z3, 1, 64);  z3 += __shfl_xor(z3, 2, 64);

    // ---------- Phase 3: out GEMM (unchanged) ----------
    const float4* pW4 = reinterpret_cast<const float4*>(postW);
    const float4* pb4 = reinterpret_cast<const float4*>(postb);
    const float4 q0w = pW4[4 * lane + 0], q1w = pW4[4 * lane + 1];
    const float4 q2w = pW4[4 * lane + 2], q3w = pW4[4 * lane + 3];
    const float4 q4w = pW4[4 * (64 + lane) + 0], q5w = pW4[4 * (64 + lane) + 1];
    const float4 q6w = pW4[4 * (64 + lane) + 2], q7w = pW4[4 * (64 + lane) + 3];
    const float4 bb0 = pb4[lane], bb1 = pb4[64 + lane];

#pragma unroll
    for (int s = 0; s < 16; ++s) {
        const float q0 = __shfl(z0, s * 4, 64);
        const float q1 = __shfl(z1, s * 4, 64);
        const float q2 = __shfl(z2, s * 4, 64);
        const float q3 = __shfl(z3, s * 4, 64);
        floatx4 o0, o1;
        o0.x = fmaf(q3, q0w.w, fmaf(q2, q0w.z, fmaf(q1, q0w.y, fmaf(q0, q0w.x, bb0.x))));
        o0.y = fmaf(q3, q1w.w, fmaf(q2, q1w.z, fmaf(q1, q1w.y, fmaf(q0, q1w.x, bb0.y))));
        o0.z = fmaf(q3, q2w.w, fmaf(q2, q2w.z, fmaf(q1, q2w.y, fmaf(q0, q2w.x, bb0.z))));
        o0.w = fmaf(q3, q3w.w, fmaf(q2, q3w.z, fmaf(q1, q3w.y, fmaf(q0, q3w.x, bb0.w))));
        o1.x = fmaf(q3, q4w.w, fmaf(q2, q4w.z, fmaf(q1, q4w.y, fmaf(q0, q4w.x, bb1.x))));
        o1.y = fmaf(q3, q5w.w, fmaf(q2, q5w.z, fmaf(q1, q5w.y, fmaf(q0, q5w.x, bb1.y))));
        o1.z = fmaf(q3, q6w.w, fmaf(q2, q6w.z, fmaf(q1, q6w.y, fmaf(q0, q6w.x, bb1.z))));
        o1.w = fmaf(q3, q7w.w, fmaf(q2, q7w.z, fmaf(q1, q7w.y, fmaf(q0, q7w.x, bb1.w))));
        float* orow = out + (size_t)(wbase + s) * 512;
        st_store4(orow + 4 * lane, o0);
        st_store4(orow + 256 + 4 * lane, o1);
    }
}

extern "C" void kernel_launch(void* const* d_in, const int* in_sizes, int n_in,
                              void* d_out, int out_size, void* d_ws, size_t ws_size,
                              hipStream_t stream)
{
    const float* x     = (const float*)d_in[0];
    const float* preW  = (const float*)d_in[1];
    const float* preb  = (const float*)d_in[2];
    const float* wts   = (const float*)d_in[3];
    const float* postW = (const float*)d_in[4];
    const float* postb = (const float*)d_in[5];
    float* out = (float*)d_out;
    const int B = in_sizes[0] / 512;

    // 4 waves/block, 64 samples/block
    k_fused<<<dim3((B + 63) / 64), dim3(256), 0, stream>>>(
        x, preW, preb, wts, postW, postb, out, B);
}